// Round 3
// baseline (1401.567 us; speedup 1.0000x reference)
//
#include <hip/hip_runtime.h>

// Problem constants (fixed by the reference setup_inputs()).
#define N_NODES 100000
#define N_EDGES 1600000
#define IN_CH   128
#define HID_CH  64
#define OUT_CH  40
#define NB      3125          // buckets of 32 nodes: 100000 = 3125*32 exactly

// ---------------------------------------------------------------------------
// zero cnt[N] + bcnt[NB]
// ---------------------------------------------------------------------------
__global__ void k_zero(int* __restrict__ cnt, int* __restrict__ bcnt) {
    int i = blockIdx.x * blockDim.x + threadIdx.x;
    if (i < N_NODES) cnt[i] = 0;
    if (i < NB) bcnt[i] = 0;
}

// ---------------------------------------------------------------------------
// histogram: per-node indegree + per-bucket edge count (4 edges/thread, int4)
// ---------------------------------------------------------------------------
__global__ void k_hist(const int* __restrict__ ei, int* __restrict__ cnt,
                       int* __restrict__ bcnt) {
    int t = blockIdx.x * blockDim.x + threadIdx.x;   // 400k threads
    if (t >= N_EDGES / 4) return;
    int4 d = ((const int4*)(ei + N_EDGES))[t];       // 4 destinations
    atomicAdd(&cnt[d.x], 1); atomicAdd(&bcnt[d.x >> 5], 1);
    atomicAdd(&cnt[d.y], 1); atomicAdd(&bcnt[d.y >> 5], 1);
    atomicAdd(&cnt[d.z], 1); atomicAdd(&bcnt[d.z >> 5], 1);
    atomicAdd(&cnt[d.w], 1); atomicAdd(&bcnt[d.w >> 5], 1);
}

// ---------------------------------------------------------------------------
// single-block scan of bcnt -> bstart (excl, NB+1), bcur (copy)
// 1024 threads x 4 elements
// ---------------------------------------------------------------------------
__global__ void k_bscan(const int* __restrict__ bcnt, int* __restrict__ bstart,
                        int* __restrict__ bcur) {
    __shared__ int s[1024];
    int t = threadIdx.x;
    int v[4];
    int sum = 0;
#pragma unroll
    for (int j = 0; j < 4; ++j) {
        int idx = t * 4 + j;
        v[j] = (idx < NB) ? bcnt[idx] : 0;
        sum += v[j];
    }
    s[t] = sum;
    __syncthreads();
    for (int off = 1; off < 1024; off <<= 1) {
        int tv = (t >= off) ? s[t - off] : 0;
        __syncthreads();
        s[t] += tv;
        __syncthreads();
    }
    int run = (t == 0) ? 0 : s[t - 1];
#pragma unroll
    for (int j = 0; j < 4; ++j) {
        int idx = t * 4 + j;
        if (idx < NB) { bstart[idx] = run; bcur[idx] = run; }
        run += v[j];
    }
    if (t == 1023) bstart[NB] = run;  // == N_EDGES
}

__global__ void k_dinv(const int* __restrict__ cnt, float* __restrict__ dinv) {
    int i = blockIdx.x * blockDim.x + threadIdx.x;
    if (i < N_NODES) dinv[i] = rsqrtf(1.0f + (float)cnt[i]);
}

// ---------------------------------------------------------------------------
// bin edges into per-bucket regions of ebuf as (src,dst) pairs
// ---------------------------------------------------------------------------
__global__ void k_bin(const int* __restrict__ ei, int* __restrict__ bcur,
                      int2* __restrict__ ebuf) {
    int e = blockIdx.x * blockDim.x + threadIdx.x;
    if (e >= N_EDGES) return;
    int s = ei[e];
    int d = ei[N_EDGES + e];
    int pos = atomicAdd(&bcur[d >> 5], 1);
    ebuf[pos] = make_int2(s, d);
}

// ---------------------------------------------------------------------------
// GEMM1 (+dinv scale): h1s[N,64] = (x[N,128] @ W1[128,64]) * dinv[row]
// ---------------------------------------------------------------------------
__global__ void k_gemm1(const float* __restrict__ x, const float* __restrict__ W1,
                        const float* __restrict__ dinv, float* __restrict__ h1s) {
    __shared__ float Wl[IN_CH * HID_CH];  // 32 KB
    int tid = threadIdx.x;
    float4* Wl4 = (float4*)Wl;
    const float4* W4 = (const float4*)W1;
    for (int i = tid; i < IN_CH * HID_CH / 4; i += 256) Wl4[i] = W4[i];
    __syncthreads();

    int row = blockIdx.x * 16 + (tid >> 4);
    int cg  = tid & 15;
    if (row >= N_NODES) return;

    const float4* xr = (const float4*)(x + (long long)row * IN_CH);
    float4 acc = {0.f, 0.f, 0.f, 0.f};
#pragma unroll
    for (int k4 = 0; k4 < IN_CH / 4; ++k4) {
        float4 xv = xr[k4];
        float4 w0 = Wl4[(k4 * 4 + 0) * 16 + cg];
        float4 w1 = Wl4[(k4 * 4 + 1) * 16 + cg];
        float4 w2 = Wl4[(k4 * 4 + 2) * 16 + cg];
        float4 w3 = Wl4[(k4 * 4 + 3) * 16 + cg];
        acc.x += xv.x * w0.x + xv.y * w1.x + xv.z * w2.x + xv.w * w3.x;
        acc.y += xv.x * w0.y + xv.y * w1.y + xv.z * w2.y + xv.w * w3.y;
        acc.z += xv.x * w0.z + xv.y * w1.z + xv.z * w2.z + xv.w * w3.z;
        acc.w += xv.x * w0.w + xv.y * w1.w + xv.z * w2.w + xv.w * w3.w;
    }
    float dd = dinv[row];
    acc.x *= dd; acc.y *= dd; acc.z *= dd; acc.w *= dd;
    ((float4*)h1s)[(long long)row * 16 + cg] = acc;
}

// ---------------------------------------------------------------------------
// bucketed aggregation layer 1: one block per bucket (32 nodes, 64 ch).
// acc[32][64] in LDS, init = self-loop row; per edge: gather + ds_add_f32.
// a1[d] = dinv[d] * acc[d]
// ---------------------------------------------------------------------------
__global__ void k_agg1b(const int* __restrict__ bstart, const int2* __restrict__ ebuf,
                        const float* __restrict__ h1s, const float* __restrict__ dinv,
                        float* __restrict__ a1) {
    __shared__ float acc[32 * 64];  // 8 KB
    int tid = threadIdx.x;
    int b = blockIdx.x;
    int node0 = b * 32;

    // init with self-loop rows (coalesced 8KB read)
#pragma unroll
    for (int i = tid; i < 32 * 64; i += 256)
        acc[i] = h1s[(long long)node0 * 64 + i];
    __syncthreads();

    int lane = tid & 63;
    int wv = tid >> 6;  // 4 waves
    int beg = bstart[b];
    int end = bstart[b + 1];

    int e = beg + wv;
    for (; e + 12 < end; e += 16) {
        int2 p0 = ebuf[e];
        int2 p1 = ebuf[e + 4];
        int2 p2 = ebuf[e + 8];
        int2 p3 = ebuf[e + 12];
        float v0 = h1s[(long long)p0.x * 64 + lane];
        float v1 = h1s[(long long)p1.x * 64 + lane];
        float v2 = h1s[(long long)p2.x * 64 + lane];
        float v3 = h1s[(long long)p3.x * 64 + lane];
        atomicAdd(&acc[(p0.y & 31) * 64 + lane], v0);
        atomicAdd(&acc[(p1.y & 31) * 64 + lane], v1);
        atomicAdd(&acc[(p2.y & 31) * 64 + lane], v2);
        atomicAdd(&acc[(p3.y & 31) * 64 + lane], v3);
    }
    for (; e < end; e += 4) {
        int2 p = ebuf[e];
        float v = h1s[(long long)p.x * 64 + lane];
        atomicAdd(&acc[(p.y & 31) * 64 + lane], v);
    }
    __syncthreads();

    // epilogue: a1 = dinv * acc (coalesced write)
#pragma unroll
    for (int i = tid; i < 32 * 64; i += 256) {
        float dd = dinv[node0 + (i >> 6)];
        a1[(long long)node0 * 64 + i] = acc[i] * dd;
    }
}

// ---------------------------------------------------------------------------
// GEMM2 (+bias/relu in, +dinv scale out): h2s = (relu(a1+b1) @ W2) * dinv
// ---------------------------------------------------------------------------
__global__ void k_gemm2(const float* __restrict__ a1, const float* __restrict__ W2,
                        const float* __restrict__ b1, const float* __restrict__ dinv,
                        float* __restrict__ h2s) {
    __shared__ float Wl[HID_CH * OUT_CH];  // 10 KB
    __shared__ float bl[HID_CH];
    int tid = threadIdx.x;
    for (int i = tid; i < HID_CH * OUT_CH / 4; i += 256)
        ((float4*)Wl)[i] = ((const float4*)W2)[i];
    if (tid < HID_CH) bl[tid] = b1[tid];
    __syncthreads();

    if (tid >= 250) return;
    int row = blockIdx.x * 25 + tid / 10;
    int cg  = tid % 10;
    if (row >= N_NODES) return;

    const float4* ar = (const float4*)(a1 + (long long)row * HID_CH);
    float4 acc = {0.f, 0.f, 0.f, 0.f};
#pragma unroll
    for (int k4 = 0; k4 < HID_CH / 4; ++k4) {
        float4 xv = ar[k4];
        xv.x = fmaxf(xv.x + bl[k4 * 4 + 0], 0.f);
        xv.y = fmaxf(xv.y + bl[k4 * 4 + 1], 0.f);
        xv.z = fmaxf(xv.z + bl[k4 * 4 + 2], 0.f);
        xv.w = fmaxf(xv.w + bl[k4 * 4 + 3], 0.f);
        float4 w0 = ((float4*)Wl)[(k4 * 4 + 0) * 10 + cg];
        float4 w1 = ((float4*)Wl)[(k4 * 4 + 1) * 10 + cg];
        float4 w2 = ((float4*)Wl)[(k4 * 4 + 2) * 10 + cg];
        float4 w3 = ((float4*)Wl)[(k4 * 4 + 3) * 10 + cg];
        acc.x += xv.x * w0.x + xv.y * w1.x + xv.z * w2.x + xv.w * w3.x;
        acc.y += xv.x * w0.y + xv.y * w1.y + xv.z * w2.y + xv.w * w3.y;
        acc.z += xv.x * w0.z + xv.y * w1.z + xv.z * w2.z + xv.w * w3.z;
        acc.w += xv.x * w0.w + xv.y * w1.w + xv.z * w2.w + xv.w * w3.w;
    }
    float dd = dinv[row];
    acc.x *= dd; acc.y *= dd; acc.z *= dd; acc.w *= dd;
    ((float4*)h2s)[(long long)row * 10 + cg] = acc;
}

// ---------------------------------------------------------------------------
// bucketed aggregation layer 2: 32 nodes x 40 ch; out = dinv*acc + b2
// ---------------------------------------------------------------------------
__global__ void k_agg2b(const int* __restrict__ bstart, const int2* __restrict__ ebuf,
                        const float* __restrict__ h2s, const float* __restrict__ dinv,
                        const float* __restrict__ b2, float* __restrict__ out) {
    __shared__ float acc[32 * 40];  // 5 KB
    int tid = threadIdx.x;
    int b = blockIdx.x;
    int node0 = b * 32;

#pragma unroll
    for (int i = tid; i < 32 * 40; i += 256)
        acc[i] = h2s[(long long)node0 * 40 + i];
    __syncthreads();

    int lane = tid & 63;
    int wv = tid >> 6;
    int beg = bstart[b];
    int end = bstart[b + 1];

    int e = beg + wv;
    for (; e + 12 < end; e += 16) {
        int2 p0 = ebuf[e];
        int2 p1 = ebuf[e + 4];
        int2 p2 = ebuf[e + 8];
        int2 p3 = ebuf[e + 12];
        if (lane < 40) {
            float v0 = h2s[(long long)p0.x * 40 + lane];
            float v1 = h2s[(long long)p1.x * 40 + lane];
            float v2 = h2s[(long long)p2.x * 40 + lane];
            float v3 = h2s[(long long)p3.x * 40 + lane];
            atomicAdd(&acc[(p0.y & 31) * 40 + lane], v0);
            atomicAdd(&acc[(p1.y & 31) * 40 + lane], v1);
            atomicAdd(&acc[(p2.y & 31) * 40 + lane], v2);
            atomicAdd(&acc[(p3.y & 31) * 40 + lane], v3);
        }
    }
    for (; e < end; e += 4) {
        int2 p = ebuf[e];
        if (lane < 40) {
            float v = h2s[(long long)p.x * 40 + lane];
            atomicAdd(&acc[(p.y & 31) * 40 + lane], v);
        }
    }
    __syncthreads();

#pragma unroll
    for (int i = tid; i < 32 * 40; i += 256) {
        int nl = i / 40;
        int ch = i % 40;
        float dd = dinv[node0 + nl];
        out[(long long)node0 * 40 + i] = acc[i] * dd + b2[ch];
    }
}

// ---------------------------------------------------------------------------
// launch
// ---------------------------------------------------------------------------
extern "C" void kernel_launch(void* const* d_in, const int* in_sizes, int n_in,
                              void* d_out, int out_size, void* d_ws, size_t ws_size,
                              hipStream_t stream) {
    const float* x  = (const float*)d_in[0];
    const int*   ei = (const int*)d_in[1];
    const float* W1 = (const float*)d_in[2];
    const float* b1 = (const float*)d_in[3];
    const float* W2 = (const float*)d_in[4];
    const float* b2 = (const float*)d_in[5];
    float* out = (float*)d_out;

    // workspace layout (int elems; keep float4 regions 16B aligned):
    // ebuf[2E] cnt[N] bcnt[3128] bstart[3128] bcur[3128] dinv[N]
    // h1s[64N] (reused as h2s) a1[64N]            total ~64.9 MB
    int* wsi = (int*)d_ws;
    int2* ebuf   = (int2*)wsi;                       // 2E ints = 12.8 MB
    int* cnt     = wsi + 2 * N_EDGES;                // N
    int* bcnt    = cnt + N_NODES;                    // 3128 (padded)
    int* bstart  = bcnt + 3128;                      // 3128 (NB+1 used)
    int* bcur    = bstart + 3128;                    // 3128
    float* dinv  = (float*)(bcur + 3128);            // N
    float* h1s   = dinv + N_NODES;                   // 64N (also h2s)
    float* a1    = h1s + (long long)N_NODES * HID_CH;// 64N
    float* h2s   = h1s;                              // alias: h1s dead after agg1

    const int B = 256;

    k_zero<<<(N_NODES + B - 1) / B, B, 0, stream>>>(cnt, bcnt);
    k_hist<<<(N_EDGES / 4 + B - 1) / B, B, 0, stream>>>(ei, cnt, bcnt);
    k_bscan<<<1, 1024, 0, stream>>>(bcnt, bstart, bcur);
    k_dinv<<<(N_NODES + B - 1) / B, B, 0, stream>>>(cnt, dinv);
    k_bin<<<(N_EDGES + B - 1) / B, B, 0, stream>>>(ei, bcur, ebuf);

    k_gemm1<<<(N_NODES + 15) / 16, B, 0, stream>>>(x, W1, dinv, h1s);
    k_agg1b<<<NB, B, 0, stream>>>(bstart, ebuf, h1s, dinv, a1);

    k_gemm2<<<(N_NODES + 24) / 25, B, 0, stream>>>(a1, W2, b1, dinv, h2s);
    k_agg2b<<<NB, B, 0, stream>>>(bstart, ebuf, h2s, dinv, b2, out);
}

// Round 4
// 388.281 us; speedup vs baseline: 3.6097x; 3.6097x over previous
//
#include <hip/hip_runtime.h>

// Problem constants (fixed by the reference setup_inputs()).
#define N_NODES 100000
#define N_EDGES 1600000
#define IN_CH   128
#define HID_CH  64
#define OUT_CH  40
#define NBLK_SCAN ((N_NODES + 255) / 256)   // 391
#define NBKT 391                            // 256-node buckets: ceil(100000/256)
#define EPB  4096                           // edges per k_bin block

// ---------------------------------------------------------------------------
// zero cnt[N]
// ---------------------------------------------------------------------------
__global__ void k_zero(int* __restrict__ cnt) {
    int i = blockIdx.x * blockDim.x + threadIdx.x;
    if (i < N_NODES) cnt[i] = 0;
}

// ---------------------------------------------------------------------------
// per-node indegree histogram (4 edges/thread, int4 loads)
// ---------------------------------------------------------------------------
__global__ void k_hist(const int* __restrict__ ei, int* __restrict__ cnt) {
    int t = blockIdx.x * blockDim.x + threadIdx.x;   // 400k threads
    if (t >= N_EDGES / 4) return;
    int4 d = ((const int4*)(ei + N_EDGES))[t];       // 4 destinations
    atomicAdd(&cnt[d.x], 1);
    atomicAdd(&cnt[d.y], 1);
    atomicAdd(&cnt[d.z], 1);
    atomicAdd(&cnt[d.w], 1);
}

// ---------------------------------------------------------------------------
// scan: per-block inclusive scan of cnt -> tmp_incl; block totals -> partial
// ---------------------------------------------------------------------------
__global__ void k_scan1(const int* __restrict__ cnt, int* __restrict__ tmp_incl,
                        int* __restrict__ partial) {
    __shared__ int s[256];
    int tid = threadIdx.x;
    int i = blockIdx.x * 256 + tid;
    s[tid] = (i < N_NODES) ? cnt[i] : 0;
    __syncthreads();
#pragma unroll
    for (int off = 1; off < 256; off <<= 1) {
        int t = (tid >= off) ? s[tid - off] : 0;
        __syncthreads();
        s[tid] += t;
        __syncthreads();
    }
    if (i < N_NODES) tmp_incl[i] = s[tid];
    if (tid == 255) partial[blockIdx.x] = s[255];
}

__global__ void k_scan2(int* __restrict__ partial) {
    __shared__ int s[512];
    int tid = threadIdx.x;
    s[tid] = (tid < NBLK_SCAN) ? partial[tid] : 0;
    __syncthreads();
#pragma unroll
    for (int off = 1; off < 512; off <<= 1) {
        int t = (tid >= off) ? s[tid - off] : 0;
        __syncthreads();
        s[tid] += t;
        __syncthreads();
    }
    if (tid < NBLK_SCAN) partial[tid] = s[tid];  // inclusive
}

// finalize: row_start, per-bucket cursor (gcur), dinv
__global__ void k_scan3(const int* __restrict__ cnt, const int* __restrict__ tmp_incl,
                        const int* __restrict__ partial, int* __restrict__ row_start,
                        int* __restrict__ gcur, float* __restrict__ dinv) {
    int i = blockIdx.x * 256 + threadIdx.x;
    if (i >= N_NODES) return;
    int b = blockIdx.x;
    int off = (b == 0) ? 0 : partial[b - 1];
    int incl = tmp_incl[i] + off;
    int c = cnt[i];
    row_start[i + 1] = incl;
    if ((i & 255) == 0) gcur[i >> 8] = incl - c;   // = row_start[i] (excl)
    dinv[i] = rsqrtf(1.0f + (float)c);
    if (i == 0) row_start[0] = 0;
}

// ---------------------------------------------------------------------------
// pass 1: block-aggregated bucket sort of edges into ebuf (src,dst) pairs.
// bucket = dst >> 8. One global atomic per (block,bucket); each block's
// writes to a bucket are contiguous -> minimal line sharing.
// ---------------------------------------------------------------------------
__global__ void k_bin(const int* __restrict__ ei, int* __restrict__ gcur,
                      int2* __restrict__ ebuf) {
    __shared__ int hist[NBKT];
    __shared__ int lcur[NBKT];
    int tid = threadIdx.x;
    int base = blockIdx.x * EPB;
    int nloc = N_EDGES - base;
    if (nloc > EPB) nloc = EPB;

    for (int i = tid; i < NBKT; i += 256) hist[i] = 0;
    __syncthreads();
    for (int i = tid; i < nloc; i += 256)
        atomicAdd(&hist[ei[N_EDGES + base + i] >> 8], 1);
    __syncthreads();
    for (int i = tid; i < NBKT; i += 256) {
        int h = hist[i];
        lcur[i] = h ? atomicAdd(&gcur[i], h) : 0;
    }
    __syncthreads();
    for (int i = tid; i < nloc; i += 256) {
        int s = ei[base + i];
        int d = ei[N_EDGES + base + i];
        int pos = atomicAdd(&lcur[d >> 8], 1);
        ebuf[pos] = make_int2(s, d);
    }
}

// ---------------------------------------------------------------------------
// pass 2: exact CSR placement within each bucket. One block per bucket;
// writes confined to a block-exclusive region of csr_src.
// ---------------------------------------------------------------------------
__global__ void k_place(const int* __restrict__ row_start, const int2* __restrict__ ebuf,
                        int* __restrict__ csr_src) {
    __shared__ int cur[256];
    int b = blockIdx.x;
    int node0 = b << 8;
    int tid = threadIdx.x;
    int node = node0 + tid;
    if (node < N_NODES) cur[tid] = row_start[node];
    __syncthreads();
    int nend = node0 + 256;
    if (nend > N_NODES) nend = N_NODES;
    int lo = row_start[node0];
    int hi = row_start[nend];
    for (int e = lo + tid; e < hi; e += 256) {
        int2 p = ebuf[e];
        int pos = atomicAdd(&cur[p.y - node0], 1);
        csr_src[pos] = p.x;
    }
}

// ---------------------------------------------------------------------------
// GEMM1 (+dinv scale): h1s[N,64] = (x[N,128] @ W1[128,64]) * dinv[row]
// ---------------------------------------------------------------------------
__global__ void k_gemm1(const float* __restrict__ x, const float* __restrict__ W1,
                        const float* __restrict__ dinv, float* __restrict__ h1s) {
    __shared__ float Wl[IN_CH * HID_CH];  // 32 KB
    int tid = threadIdx.x;
    float4* Wl4 = (float4*)Wl;
    const float4* W4 = (const float4*)W1;
    for (int i = tid; i < IN_CH * HID_CH / 4; i += 256) Wl4[i] = W4[i];
    __syncthreads();

    int row = blockIdx.x * 16 + (tid >> 4);
    int cg  = tid & 15;
    if (row >= N_NODES) return;

    const float4* xr = (const float4*)(x + (long long)row * IN_CH);
    float4 acc = {0.f, 0.f, 0.f, 0.f};
#pragma unroll
    for (int k4 = 0; k4 < IN_CH / 4; ++k4) {
        float4 xv = xr[k4];
        float4 w0 = Wl4[(k4 * 4 + 0) * 16 + cg];
        float4 w1 = Wl4[(k4 * 4 + 1) * 16 + cg];
        float4 w2 = Wl4[(k4 * 4 + 2) * 16 + cg];
        float4 w3 = Wl4[(k4 * 4 + 3) * 16 + cg];
        acc.x += xv.x * w0.x + xv.y * w1.x + xv.z * w2.x + xv.w * w3.x;
        acc.y += xv.x * w0.y + xv.y * w1.y + xv.z * w2.y + xv.w * w3.y;
        acc.z += xv.x * w0.z + xv.y * w1.z + xv.z * w2.z + xv.w * w3.z;
        acc.w += xv.x * w0.w + xv.y * w1.w + xv.z * w2.w + xv.w * w3.w;
    }
    float dd = dinv[row];
    acc.x *= dd; acc.y *= dd; acc.z *= dd; acc.w *= dd;
    ((float4*)h1s)[(long long)row * 16 + cg] = acc;
}

// ---------------------------------------------------------------------------
// CSR aggregation layer 1 (register accumulate, unroll 4):
// a1[d] = dinv[d] * (h1s[d] + sum_{s in N(d)} h1s[s])
// ---------------------------------------------------------------------------
__global__ void k_agg1(const int* __restrict__ row_start, const int* __restrict__ csr_src,
                       const float* __restrict__ h1s, const float* __restrict__ dinv,
                       float* __restrict__ a1) {
    int idx = blockIdx.x * blockDim.x + threadIdx.x;
    int node = idx >> 4;
    int cg = idx & 15;
    if (node >= N_NODES) return;
    int beg = row_start[node];
    int end = row_start[node + 1];
    const float4* H = (const float4*)h1s;
    float4 acc = H[(long long)node * 16 + cg];  // self-loop
    int e = beg;
    for (; e + 3 < end; e += 4) {
        int s0 = csr_src[e];
        int s1 = csr_src[e + 1];
        int s2 = csr_src[e + 2];
        int s3 = csr_src[e + 3];
        float4 v0 = H[(long long)s0 * 16 + cg];
        float4 v1 = H[(long long)s1 * 16 + cg];
        float4 v2 = H[(long long)s2 * 16 + cg];
        float4 v3 = H[(long long)s3 * 16 + cg];
        acc.x += (v0.x + v1.x) + (v2.x + v3.x);
        acc.y += (v0.y + v1.y) + (v2.y + v3.y);
        acc.z += (v0.z + v1.z) + (v2.z + v3.z);
        acc.w += (v0.w + v1.w) + (v2.w + v3.w);
    }
    for (; e < end; ++e) {
        int s = csr_src[e];
        float4 v = H[(long long)s * 16 + cg];
        acc.x += v.x; acc.y += v.y; acc.z += v.z; acc.w += v.w;
    }
    float dd = dinv[node];
    acc.x *= dd; acc.y *= dd; acc.z *= dd; acc.w *= dd;
    ((float4*)a1)[(long long)node * 16 + cg] = acc;
}

// ---------------------------------------------------------------------------
// GEMM2 (+bias/relu in, +dinv scale out): h2s = (relu(a1+b1) @ W2) * dinv
// ---------------------------------------------------------------------------
__global__ void k_gemm2(const float* __restrict__ a1, const float* __restrict__ W2,
                        const float* __restrict__ b1, const float* __restrict__ dinv,
                        float* __restrict__ h2s) {
    __shared__ float Wl[HID_CH * OUT_CH];  // 10 KB
    __shared__ float bl[HID_CH];
    int tid = threadIdx.x;
    for (int i = tid; i < HID_CH * OUT_CH / 4; i += 256)
        ((float4*)Wl)[i] = ((const float4*)W2)[i];
    if (tid < HID_CH) bl[tid] = b1[tid];
    __syncthreads();

    if (tid >= 250) return;
    int row = blockIdx.x * 25 + tid / 10;
    int cg  = tid % 10;
    if (row >= N_NODES) return;

    const float4* ar = (const float4*)(a1 + (long long)row * HID_CH);
    float4 acc = {0.f, 0.f, 0.f, 0.f};
#pragma unroll
    for (int k4 = 0; k4 < HID_CH / 4; ++k4) {
        float4 xv = ar[k4];
        xv.x = fmaxf(xv.x + bl[k4 * 4 + 0], 0.f);
        xv.y = fmaxf(xv.y + bl[k4 * 4 + 1], 0.f);
        xv.z = fmaxf(xv.z + bl[k4 * 4 + 2], 0.f);
        xv.w = fmaxf(xv.w + bl[k4 * 4 + 3], 0.f);
        float4 w0 = ((float4*)Wl)[(k4 * 4 + 0) * 10 + cg];
        float4 w1 = ((float4*)Wl)[(k4 * 4 + 1) * 10 + cg];
        float4 w2 = ((float4*)Wl)[(k4 * 4 + 2) * 10 + cg];
        float4 w3 = ((float4*)Wl)[(k4 * 4 + 3) * 10 + cg];
        acc.x += xv.x * w0.x + xv.y * w1.x + xv.z * w2.x + xv.w * w3.x;
        acc.y += xv.x * w0.y + xv.y * w1.y + xv.z * w2.y + xv.w * w3.y;
        acc.z += xv.x * w0.z + xv.y * w1.z + xv.z * w2.z + xv.w * w3.z;
        acc.w += xv.x * w0.w + xv.y * w1.w + xv.z * w2.w + xv.w * w3.w;
    }
    float dd = dinv[row];
    acc.x *= dd; acc.y *= dd; acc.z *= dd; acc.w *= dd;
    ((float4*)h2s)[(long long)row * 10 + cg] = acc;
}

// ---------------------------------------------------------------------------
// CSR aggregation layer 2 (+bias, unroll 4): out = dinv*(self+sum) + b2
// ---------------------------------------------------------------------------
__global__ void k_agg2(const int* __restrict__ row_start, const int* __restrict__ csr_src,
                       const float* __restrict__ h2s, const float* __restrict__ dinv,
                       const float* __restrict__ b2, float* __restrict__ out) {
    int idx = blockIdx.x * blockDim.x + threadIdx.x;
    int node = idx >> 4;
    int cg = idx & 15;
    if (node >= N_NODES || cg >= 10) return;
    int beg = row_start[node];
    int end = row_start[node + 1];
    const float4* H = (const float4*)h2s;
    float4 acc = H[(long long)node * 10 + cg];  // self-loop
    int e = beg;
    for (; e + 3 < end; e += 4) {
        int s0 = csr_src[e];
        int s1 = csr_src[e + 1];
        int s2 = csr_src[e + 2];
        int s3 = csr_src[e + 3];
        float4 v0 = H[(long long)s0 * 10 + cg];
        float4 v1 = H[(long long)s1 * 10 + cg];
        float4 v2 = H[(long long)s2 * 10 + cg];
        float4 v3 = H[(long long)s3 * 10 + cg];
        acc.x += (v0.x + v1.x) + (v2.x + v3.x);
        acc.y += (v0.y + v1.y) + (v2.y + v3.y);
        acc.z += (v0.z + v1.z) + (v2.z + v3.z);
        acc.w += (v0.w + v1.w) + (v2.w + v3.w);
    }
    for (; e < end; ++e) {
        int s = csr_src[e];
        float4 v = H[(long long)s * 10 + cg];
        acc.x += v.x; acc.y += v.y; acc.z += v.z; acc.w += v.w;
    }
    float dd = dinv[node];
    float4 b = ((const float4*)b2)[cg];
    acc.x = acc.x * dd + b.x;
    acc.y = acc.y * dd + b.y;
    acc.z = acc.z * dd + b.z;
    acc.w = acc.w * dd + b.w;
    ((float4*)out)[(long long)node * 10 + cg] = acc;
}

// ---------------------------------------------------------------------------
// launch
// ---------------------------------------------------------------------------
extern "C" void kernel_launch(void* const* d_in, const int* in_sizes, int n_in,
                              void* d_out, int out_size, void* d_ws, size_t ws_size,
                              hipStream_t stream) {
    const float* x  = (const float*)d_in[0];
    const int*   ei = (const int*)d_in[1];
    const float* W1 = (const float*)d_in[2];
    const float* b1 = (const float*)d_in[3];
    const float* W2 = (const float*)d_in[4];
    const float* b2 = (const float*)d_in[5];
    float* out = (float*)d_out;

    // workspace layout (4B units; float4 arrays 16B-aligned at front):
    // h1s[64N] (reused as h2s) | a1[64N] | ebuf int2[E] | csr_src[E] |
    // cnt[N] | tmp_incl[N] | partial[512] | row_start[N+4] | gcur[400] | dinv[N]
    // total ~72 MB
    float* wsf = (float*)d_ws;
    float* h1s  = wsf;                                   // 64N
    float* a1   = h1s + (long long)N_NODES * HID_CH;     // 64N
    float* h2s  = h1s;                                   // alias (h1s dead after agg1)
    int* wsi       = (int*)(a1 + (long long)N_NODES * HID_CH);
    int2* ebuf     = (int2*)wsi;                         // 2E ints
    int* csr_src   = wsi + 2 * N_EDGES;                  // E
    int* cnt       = csr_src + N_EDGES;                  // N
    int* tmp_incl  = cnt + N_NODES;                      // N
    int* partial   = tmp_incl + N_NODES;                 // 512
    int* row_start = partial + 512;                      // N+4
    int* gcur      = row_start + N_NODES + 4;            // 400
    float* dinv    = (float*)(gcur + 400);               // N

    const int B = 256;
    const int gN  = (N_NODES + B - 1) / B;
    const int g16 = (N_NODES * 16 + B - 1) / B;

    // CSR build + dinv
    k_zero<<<gN, B, 0, stream>>>(cnt);
    k_hist<<<(N_EDGES / 4 + B - 1) / B, B, 0, stream>>>(ei, cnt);
    k_scan1<<<NBLK_SCAN, 256, 0, stream>>>(cnt, tmp_incl, partial);
    k_scan2<<<1, 512, 0, stream>>>(partial);
    k_scan3<<<NBLK_SCAN, 256, 0, stream>>>(cnt, tmp_incl, partial, row_start, gcur, dinv);
    k_bin<<<(N_EDGES + EPB - 1) / EPB, B, 0, stream>>>(ei, gcur, ebuf);
    k_place<<<NBKT, B, 0, stream>>>(row_start, ebuf, csr_src);

    // layer 1
    k_gemm1<<<(N_NODES + 15) / 16, B, 0, stream>>>(x, W1, dinv, h1s);
    k_agg1<<<g16, B, 0, stream>>>(row_start, csr_src, h1s, dinv, a1);

    // layer 2
    k_gemm2<<<(N_NODES + 24) / 25, B, 0, stream>>>(a1, W2, b1, dinv, h2s);
    k_agg2<<<g16, B, 0, stream>>>(row_start, csr_src, h2s, dinv, b2, out);
}

// Round 5
// 289.288 us; speedup vs baseline: 4.8449x; 1.3422x over previous
//
#include <hip/hip_runtime.h>

// Problem constants (fixed by the reference setup_inputs()).
#define N_NODES 100000
#define N_EDGES 1600000
#define IN_CH   128
#define HID_CH  64
#define OUT_CH  40
#define NBKT    391     // ceil(100000/256) buckets of 256 nodes
#define EPB     4096    // edges per k_bin block

// bf16 helpers (tables are bf16; all accumulation fp32)
__device__ __forceinline__ float bf2f(unsigned short u) {
    union { unsigned int i; float f; } c; c.i = ((unsigned int)u) << 16; return c.f;
}
__device__ __forceinline__ unsigned short f2bf(float f) {
    union { float f; unsigned int i; } c; c.f = f;
    unsigned int r = c.i + 0x7FFFu + ((c.i >> 16) & 1u);  // RNE
    return (unsigned short)(r >> 16);
}
__device__ __forceinline__ float4 bf2f4(ushort4 u) {
    return make_float4(bf2f(u.x), bf2f(u.y), bf2f(u.z), bf2f(u.w));
}

// ---------------------------------------------------------------------------
// zero bucket counters
// ---------------------------------------------------------------------------
__global__ void k_zerob(int* __restrict__ bcnt) {
    if (threadIdx.x < NBKT) bcnt[threadIdx.x] = 0;
}

// ---------------------------------------------------------------------------
// bucket histogram: LDS-aggregated, ~391 global atomics per block
// ---------------------------------------------------------------------------
__global__ void k_bhist(const int* __restrict__ ei, int* __restrict__ bcnt) {
    __shared__ int h[NBKT];
    int tid = threadIdx.x;
    for (int i = tid; i < NBKT; i += 256) h[i] = 0;
    __syncthreads();
    const int4* d4 = (const int4*)(ei + N_EDGES);
    int stride = gridDim.x * 256;
    for (int t = blockIdx.x * 256 + tid; t < N_EDGES / 4; t += stride) {
        int4 d = d4[t];
        atomicAdd(&h[d.x >> 8], 1);
        atomicAdd(&h[d.y >> 8], 1);
        atomicAdd(&h[d.z >> 8], 1);
        atomicAdd(&h[d.w >> 8], 1);
    }
    __syncthreads();
    for (int i = tid; i < NBKT; i += 256)
        if (h[i]) atomicAdd(&bcnt[i], h[i]);
}

// ---------------------------------------------------------------------------
// single-block scan of bcnt -> bstart (excl, NBKT+1) + gcur copy
// ---------------------------------------------------------------------------
__global__ void k_bscan(const int* __restrict__ bcnt, int* __restrict__ bstart,
                        int* __restrict__ gcur) {
    __shared__ int s[512];
    int t = threadIdx.x;
    int v = (t < NBKT) ? bcnt[t] : 0;
    s[t] = v;
    __syncthreads();
#pragma unroll
    for (int off = 1; off < 512; off <<= 1) {
        int tv = (t >= off) ? s[t - off] : 0;
        __syncthreads();
        s[t] += tv;
        __syncthreads();
    }
    if (t < NBKT) { int excl = s[t] - v; bstart[t] = excl; gcur[t] = excl; }
    if (t == NBKT - 1) bstart[NBKT] = s[t];  // == N_EDGES
}

// ---------------------------------------------------------------------------
// bin edges into bucket regions, packed: word = src | ((dst&255)<<20)
// (src < 2^17 fits in 20 bits)
// ---------------------------------------------------------------------------
__global__ void k_bin(const int* __restrict__ ei, int* __restrict__ gcur,
                      int* __restrict__ ebuf) {
    __shared__ int hist[NBKT];
    __shared__ int lcur[NBKT];
    int tid = threadIdx.x;
    int base = blockIdx.x * EPB;
    int nloc = N_EDGES - base;
    if (nloc > EPB) nloc = EPB;

    for (int i = tid; i < NBKT; i += 256) hist[i] = 0;
    __syncthreads();
    for (int i = tid; i < nloc; i += 256)
        atomicAdd(&hist[ei[N_EDGES + base + i] >> 8], 1);
    __syncthreads();
    for (int i = tid; i < NBKT; i += 256) {
        int h = hist[i];
        lcur[i] = h ? atomicAdd(&gcur[i], h) : 0;
    }
    __syncthreads();
    for (int i = tid; i < nloc; i += 256) {
        int s = ei[base + i];
        int d = ei[N_EDGES + base + i];
        int pos = atomicAdd(&lcur[d >> 8], 1);
        ebuf[pos] = s | ((d & 255) << 20);
    }
}

// ---------------------------------------------------------------------------
// per-bucket: count 256 nodes in LDS, scan, emit row_start/dinv, place edges
// into exact CSR order. All heavy atomics are LDS; writes block-exclusive.
// ---------------------------------------------------------------------------
__global__ void k_node(const int* __restrict__ bstart, const int* __restrict__ ebuf,
                       int* __restrict__ row_start, int* __restrict__ csr_src,
                       float* __restrict__ dinv) {
    __shared__ int cnt[256];
    __shared__ int s[256];
    int tid = threadIdx.x;
    int b = blockIdx.x;
    int node0 = b << 8;
    int lo = bstart[b], hi = bstart[b + 1];

    cnt[tid] = 0;
    __syncthreads();
    for (int e = lo + tid; e < hi; e += 256)
        atomicAdd(&cnt[(unsigned)ebuf[e] >> 20], 1);
    __syncthreads();
    int c = cnt[tid];
    s[tid] = c;
    __syncthreads();
#pragma unroll
    for (int off = 1; off < 256; off <<= 1) {
        int tv = (tid >= off) ? s[tid - off] : 0;
        __syncthreads();
        s[tid] += tv;
        __syncthreads();
    }
    int excl = lo + s[tid] - c;
    int node = node0 + tid;
    if (node < N_NODES) {
        row_start[node] = excl;
        dinv[node] = rsqrtf(1.0f + (float)c);
    }
    if (b == NBKT - 1 && tid == 255) row_start[N_NODES] = hi;
    __syncthreads();
    cnt[tid] = excl;  // reuse as cursor
    __syncthreads();
    for (int e = lo + tid; e < hi; e += 256) {
        int w = ebuf[e];
        int pos = atomicAdd(&cnt[(unsigned)w >> 20], 1);
        csr_src[pos] = w & 0xFFFFF;
    }
}

// ---------------------------------------------------------------------------
// GEMM1 (+dinv scale, bf16 out): h1s[N,64] = bf16((x @ W1) * dinv[row])
// ---------------------------------------------------------------------------
__global__ void k_gemm1(const float* __restrict__ x, const float* __restrict__ W1,
                        const float* __restrict__ dinv, unsigned short* __restrict__ h1s) {
    __shared__ float Wl[IN_CH * HID_CH];  // 32 KB
    int tid = threadIdx.x;
    float4* Wl4 = (float4*)Wl;
    const float4* W4 = (const float4*)W1;
    for (int i = tid; i < IN_CH * HID_CH / 4; i += 256) Wl4[i] = W4[i];
    __syncthreads();

    int row = blockIdx.x * 16 + (tid >> 4);
    int cg  = tid & 15;
    if (row >= N_NODES) return;

    const float4* xr = (const float4*)(x + (long long)row * IN_CH);
    float4 acc = {0.f, 0.f, 0.f, 0.f};
#pragma unroll
    for (int k4 = 0; k4 < IN_CH / 4; ++k4) {
        float4 xv = xr[k4];
        float4 w0 = Wl4[(k4 * 4 + 0) * 16 + cg];
        float4 w1 = Wl4[(k4 * 4 + 1) * 16 + cg];
        float4 w2 = Wl4[(k4 * 4 + 2) * 16 + cg];
        float4 w3 = Wl4[(k4 * 4 + 3) * 16 + cg];
        acc.x += xv.x * w0.x + xv.y * w1.x + xv.z * w2.x + xv.w * w3.x;
        acc.y += xv.x * w0.y + xv.y * w1.y + xv.z * w2.y + xv.w * w3.y;
        acc.z += xv.x * w0.z + xv.y * w1.z + xv.z * w2.z + xv.w * w3.z;
        acc.w += xv.x * w0.w + xv.y * w1.w + xv.z * w2.w + xv.w * w3.w;
    }
    float dd = dinv[row];
    ((ushort4*)h1s)[(long long)row * 16 + cg] =
        make_ushort4(f2bf(acc.x * dd), f2bf(acc.y * dd), f2bf(acc.z * dd), f2bf(acc.w * dd));
}

// ---------------------------------------------------------------------------
// CSR aggregation layer 1 (bf16 gather, fp32 acc, unroll 4):
// a1[d] = dinv[d] * (h1s[d] + sum_{s in N(d)} h1s[s])
// ---------------------------------------------------------------------------
__global__ void k_agg1(const int* __restrict__ row_start, const int* __restrict__ csr_src,
                       const unsigned short* __restrict__ h1s, const float* __restrict__ dinv,
                       float* __restrict__ a1) {
    int idx = blockIdx.x * blockDim.x + threadIdx.x;
    int node = idx >> 4;
    int cg = idx & 15;
    if (node >= N_NODES) return;
    int beg = row_start[node];
    int end = row_start[node + 1];
    const ushort4* H = (const ushort4*)h1s;
    float4 acc = bf2f4(H[(long long)node * 16 + cg]);  // self-loop
    int e = beg;
    for (; e + 3 < end; e += 4) {
        int s0 = csr_src[e];
        int s1 = csr_src[e + 1];
        int s2 = csr_src[e + 2];
        int s3 = csr_src[e + 3];
        float4 v0 = bf2f4(H[(long long)s0 * 16 + cg]);
        float4 v1 = bf2f4(H[(long long)s1 * 16 + cg]);
        float4 v2 = bf2f4(H[(long long)s2 * 16 + cg]);
        float4 v3 = bf2f4(H[(long long)s3 * 16 + cg]);
        acc.x += (v0.x + v1.x) + (v2.x + v3.x);
        acc.y += (v0.y + v1.y) + (v2.y + v3.y);
        acc.z += (v0.z + v1.z) + (v2.z + v3.z);
        acc.w += (v0.w + v1.w) + (v2.w + v3.w);
    }
    for (; e < end; ++e) {
        float4 v = bf2f4(H[(long long)csr_src[e] * 16 + cg]);
        acc.x += v.x; acc.y += v.y; acc.z += v.z; acc.w += v.w;
    }
    float dd = dinv[node];
    acc.x *= dd; acc.y *= dd; acc.z *= dd; acc.w *= dd;
    ((float4*)a1)[(long long)node * 16 + cg] = acc;
}

// ---------------------------------------------------------------------------
// GEMM2 (+bias/relu in, +dinv scale, bf16 out): h2s = bf16((relu(a1+b1)@W2)*dinv)
// ---------------------------------------------------------------------------
__global__ void k_gemm2(const float* __restrict__ a1, const float* __restrict__ W2,
                        const float* __restrict__ b1, const float* __restrict__ dinv,
                        unsigned short* __restrict__ h2s) {
    __shared__ float Wl[HID_CH * OUT_CH];  // 10 KB
    __shared__ float bl[HID_CH];
    int tid = threadIdx.x;
    for (int i = tid; i < HID_CH * OUT_CH / 4; i += 256)
        ((float4*)Wl)[i] = ((const float4*)W2)[i];
    if (tid < HID_CH) bl[tid] = b1[tid];
    __syncthreads();

    if (tid >= 250) return;
    int row = blockIdx.x * 25 + tid / 10;
    int cg  = tid % 10;
    if (row >= N_NODES) return;

    const float4* ar = (const float4*)(a1 + (long long)row * HID_CH);
    float4 acc = {0.f, 0.f, 0.f, 0.f};
#pragma unroll
    for (int k4 = 0; k4 < HID_CH / 4; ++k4) {
        float4 xv = ar[k4];
        xv.x = fmaxf(xv.x + bl[k4 * 4 + 0], 0.f);
        xv.y = fmaxf(xv.y + bl[k4 * 4 + 1], 0.f);
        xv.z = fmaxf(xv.z + bl[k4 * 4 + 2], 0.f);
        xv.w = fmaxf(xv.w + bl[k4 * 4 + 3], 0.f);
        float4 w0 = ((float4*)Wl)[(k4 * 4 + 0) * 10 + cg];
        float4 w1 = ((float4*)Wl)[(k4 * 4 + 1) * 10 + cg];
        float4 w2 = ((float4*)Wl)[(k4 * 4 + 2) * 10 + cg];
        float4 w3 = ((float4*)Wl)[(k4 * 4 + 3) * 10 + cg];
        acc.x += xv.x * w0.x + xv.y * w1.x + xv.z * w2.x + xv.w * w3.x;
        acc.y += xv.x * w0.y + xv.y * w1.y + xv.z * w2.y + xv.w * w3.y;
        acc.z += xv.x * w0.z + xv.y * w1.z + xv.z * w2.z + xv.w * w3.z;
        acc.w += xv.x * w0.w + xv.y * w1.w + xv.z * w2.w + xv.w * w3.w;
    }
    float dd = dinv[row];
    ((ushort4*)h2s)[(long long)row * 10 + cg] =
        make_ushort4(f2bf(acc.x * dd), f2bf(acc.y * dd), f2bf(acc.z * dd), f2bf(acc.w * dd));
}

// ---------------------------------------------------------------------------
// CSR aggregation layer 2 (+bias, bf16 gather, unroll 4)
// ---------------------------------------------------------------------------
__global__ void k_agg2(const int* __restrict__ row_start, const int* __restrict__ csr_src,
                       const unsigned short* __restrict__ h2s, const float* __restrict__ dinv,
                       const float* __restrict__ b2, float* __restrict__ out) {
    int idx = blockIdx.x * blockDim.x + threadIdx.x;
    int node = idx >> 4;
    int cg = idx & 15;
    if (node >= N_NODES || cg >= 10) return;
    int beg = row_start[node];
    int end = row_start[node + 1];
    const ushort4* H = (const ushort4*)h2s;
    float4 acc = bf2f4(H[(long long)node * 10 + cg]);  // self-loop
    int e = beg;
    for (; e + 3 < end; e += 4) {
        int s0 = csr_src[e];
        int s1 = csr_src[e + 1];
        int s2 = csr_src[e + 2];
        int s3 = csr_src[e + 3];
        float4 v0 = bf2f4(H[(long long)s0 * 10 + cg]);
        float4 v1 = bf2f4(H[(long long)s1 * 10 + cg]);
        float4 v2 = bf2f4(H[(long long)s2 * 10 + cg]);
        float4 v3 = bf2f4(H[(long long)s3 * 10 + cg]);
        acc.x += (v0.x + v1.x) + (v2.x + v3.x);
        acc.y += (v0.y + v1.y) + (v2.y + v3.y);
        acc.z += (v0.z + v1.z) + (v2.z + v3.z);
        acc.w += (v0.w + v1.w) + (v2.w + v3.w);
    }
    for (; e < end; ++e) {
        float4 v = bf2f4(H[(long long)csr_src[e] * 10 + cg]);
        acc.x += v.x; acc.y += v.y; acc.z += v.z; acc.w += v.w;
    }
    float dd = dinv[node];
    float4 b = ((const float4*)b2)[cg];
    acc.x = acc.x * dd + b.x;
    acc.y = acc.y * dd + b.y;
    acc.z = acc.z * dd + b.z;
    acc.w = acc.w * dd + b.w;
    ((float4*)out)[(long long)node * 10 + cg] = acc;
}

// ---------------------------------------------------------------------------
// launch
// ---------------------------------------------------------------------------
extern "C" void kernel_launch(void* const* d_in, const int* in_sizes, int n_in,
                              void* d_out, int out_size, void* d_ws, size_t ws_size,
                              hipStream_t stream) {
    const float* x  = (const float*)d_in[0];
    const int*   ei = (const int*)d_in[1];
    const float* W1 = (const float*)d_in[2];
    const float* b1 = (const float*)d_in[3];
    const float* W2 = (const float*)d_in[4];
    const float* b2 = (const float*)d_in[5];
    float* out = (float*)d_out;

    // workspace layout (16B-aligned regions):
    // a1 fp32[64N] | hbuf bf16[64N] (h1s, reused as h2s) | ebuf[E] | csr_src[E]
    // | row_start[N+4] | bcnt[400] | bstart[400] | gcur[400] | dinv[N]  ~52 MB
    float* a1 = (float*)d_ws;                                     // 64N fp32
    unsigned short* hbuf = (unsigned short*)(a1 + 64LL * N_NODES);// 64N bf16
    int* ebuf      = (int*)(hbuf + 64LL * N_NODES);               // E
    int* csr_src   = ebuf + N_EDGES;                              // E
    int* row_start = csr_src + N_EDGES;                           // N+4
    int* bcnt      = row_start + N_NODES + 4;                     // 400
    int* bstart    = bcnt + 400;                                  // 400 (NBKT+1)
    int* gcur      = bstart + 400;                                // 400
    float* dinv    = (float*)(gcur + 400);                        // N

    const int B = 256;
    const int g16 = (N_NODES * 16 + B - 1) / B;

    // CSR build + dinv (bucket-local counting; no 100k-wide scan)
    k_zerob<<<1, 512, 0, stream>>>(bcnt);
    k_bhist<<<400, B, 0, stream>>>(ei, bcnt);
    k_bscan<<<1, 512, 0, stream>>>(bcnt, bstart, gcur);
    k_bin<<<(N_EDGES + EPB - 1) / EPB, B, 0, stream>>>(ei, gcur, ebuf);
    k_node<<<NBKT, B, 0, stream>>>(bstart, ebuf, row_start, csr_src, dinv);

    // layer 1
    k_gemm1<<<(N_NODES + 15) / 16, B, 0, stream>>>(x, W1, dinv, hbuf);
    k_agg1<<<g16, B, 0, stream>>>(row_start, csr_src, hbuf, dinv, a1);

    // layer 2 (hbuf reused for h2s: h1s dead after agg1)
    k_gemm2<<<(N_NODES + 24) / 25, B, 0, stream>>>(a1, W2, b1, dinv, hbuf);
    k_agg2<<<g16, B, 0, stream>>>(row_start, csr_src, hbuf, dinv, b2, out);
}